// Round 2
// 972.406 us; speedup vs baseline: 1.1673x; 1.1673x over previous
//
#include <hip/hip_runtime.h>
#include <stdint.h>

// Problem constants (from reference)
#define O_DIM 4096
#define I_DIM 4096
#define NB_DIM 128
#define R_DIM 16
#define M_DIM 16384          // B*S = 8*2048
#define NT_K 64              // K tiles of 64
#define LORA_SCALE 0.5f
#define Q_ZERO 128.0f

typedef short bf16x8 __attribute__((ext_vector_type(8)));
typedef float f32x4 __attribute__((ext_vector_type(4)));

__device__ __forceinline__ uint16_t f2bf(float f) {
    union { float f; uint32_t u; } v; v.f = f;
    uint32_t u = v.u;
    return (uint16_t)((u + 0x7fffu + ((u >> 16) & 1u)) >> 16);   // RNE
}

__device__ __forceinline__ void gll16(const void* g, void* l) {
    __builtin_amdgcn_global_load_lds(
        (const __attribute__((address_space(1))) void*)g,
        (__attribute__((address_space(3))) void*)l, 16, 0, 0);
}

// ---------------------------------------------------------------------------
// Kernel 1: W = scales * (q - 128) + 0.5 * up @ down  -> bf16 [O, I]
// ---------------------------------------------------------------------------
__global__ void build_w_kernel(const int* __restrict__ qw,
                               const float* __restrict__ scales,
                               const float* __restrict__ up,
                               const float* __restrict__ down,
                               uint16_t* __restrict__ wout) {
    int idx = blockIdx.x * 256 + threadIdx.x;       // [0, O*I/4)
    int i4  = idx & (I_DIM / 4 - 1);                // I/4 = 1024
    int o   = idx >> 10;
    int4 q = ((const int4*)qw)[(size_t)o * (I_DIM / 4) + i4];
    float scale = scales[o * NB_DIM + (i4 >> 3)];   // block = (i4*4)/32
    float a0 = 0.f, a1 = 0.f, a2 = 0.f, a3 = 0.f;
#pragma unroll
    for (int r = 0; r < R_DIM; ++r) {
        float u = up[o * R_DIM + r];
        float4 d = ((const float4*)down)[r * (I_DIM / 4) + i4];
        a0 += u * d.x; a1 += u * d.y; a2 += u * d.z; a3 += u * d.w;
    }
    float w0 = scale * ((float)q.x - Q_ZERO) + LORA_SCALE * a0;
    float w1 = scale * ((float)q.y - Q_ZERO) + LORA_SCALE * a1;
    float w2 = scale * ((float)q.z - Q_ZERO) + LORA_SCALE * a2;
    float w3 = scale * ((float)q.w - Q_ZERO) + LORA_SCALE * a3;
    ushort4 outv = { f2bf(w0), f2bf(w1), f2bf(w2), f2bf(w3) };
    ((ushort4*)wout)[(size_t)o * (I_DIM / 4) + i4] = outv;
}

// ---------------------------------------------------------------------------
// Kernel 2: x f32 -> bf16, 8 elems/thread
// ---------------------------------------------------------------------------
__global__ void cvt_x_kernel(const float* __restrict__ x,
                             uint16_t* __restrict__ xb) {
    size_t idx = (size_t)blockIdx.x * 256 + threadIdx.x;   // [0, M*I/8)
    float4 a = ((const float4*)x)[idx * 2];
    float4 b = ((const float4*)x)[idx * 2 + 1];
    ushort4 o0 = { f2bf(a.x), f2bf(a.y), f2bf(a.z), f2bf(a.w) };
    ushort4 o1 = { f2bf(b.x), f2bf(b.y), f2bf(b.z), f2bf(b.w) };
    ((ushort4*)xb)[idx * 2] = o0;
    ((ushort4*)xb)[idx * 2 + 1] = o1;
}

// ---------------------------------------------------------------------------
// Kernel 3 (fallback, small ws): m97-structure 128x128 tile GEMM, f32 A path.
// ---------------------------------------------------------------------------
__global__ void gemm_kernel_f32a(const float* __restrict__ Af,
                                 const uint16_t* __restrict__ Wb,
                                 const float* __restrict__ bias,
                                 float* __restrict__ out) {
    __shared__ __align__(16) uint16_t As[128 * 32];
    __shared__ __align__(16) uint16_t Bs[128 * 32];
    const int tid = threadIdx.x;
    const int wave = tid >> 6, lane = tid & 63;
    const int m0 = blockIdx.y * 128;
    const int n0 = blockIdx.x * 128;
    const int wr = wave >> 1, wc = wave & 1;

    f32x4 acc[4][4] = {};
    const int lrow = lane & 15;
    const int lk = (lane >> 4) * 8;

    for (int k0 = 0; k0 < I_DIM; k0 += 32) {
        {
            int row = tid >> 1;
            int col0 = (tid & 1) * 16;
            const float4* gp =
                (const float4*)(Af + (size_t)(m0 + row) * I_DIM + k0 + col0);
            float4 v0 = gp[0], v1 = gp[1], v2 = gp[2], v3 = gp[3];
            ushort4* dst = (ushort4*)&As[row * 32 + col0];
            ushort4 s0 = { f2bf(v0.x), f2bf(v0.y), f2bf(v0.z), f2bf(v0.w) };
            ushort4 s1 = { f2bf(v1.x), f2bf(v1.y), f2bf(v1.z), f2bf(v1.w) };
            ushort4 s2 = { f2bf(v2.x), f2bf(v2.y), f2bf(v2.z), f2bf(v2.w) };
            ushort4 s3 = { f2bf(v3.x), f2bf(v3.y), f2bf(v3.z), f2bf(v3.w) };
            dst[0] = s0; dst[1] = s1; dst[2] = s2; dst[3] = s3;
        }
#pragma unroll
        for (int j = 0; j < 2; ++j) {
            int slot = wave * 2 + j;
            int row = slot * 16 + (lane >> 2);
            int col = (lane & 3) * 8;
            gll16(Wb + (size_t)(n0 + row) * I_DIM + k0 + col,
                  Bs + slot * 512);
        }
        __syncthreads();
        bf16x8 a[4], b[4];
#pragma unroll
        for (int mi = 0; mi < 4; ++mi)
            a[mi] = *(const bf16x8*)&As[(wr * 64 + mi * 16 + lrow) * 32 + lk];
#pragma unroll
        for (int ni = 0; ni < 4; ++ni)
            b[ni] = *(const bf16x8*)&Bs[(wc * 64 + ni * 16 + lrow) * 32 + lk];
#pragma unroll
        for (int mi = 0; mi < 4; ++mi)
#pragma unroll
            for (int ni = 0; ni < 4; ++ni)
                acc[mi][ni] = __builtin_amdgcn_mfma_f32_16x16x32_bf16(
                    a[mi], b[ni], acc[mi][ni], 0, 0, 0);
        __syncthreads();
    }

    const int lcol = lane & 15;
    const int lquad = lane >> 4;
#pragma unroll
    for (int ni = 0; ni < 4; ++ni) {
        int n = n0 + wc * 64 + ni * 16 + lcol;
        float bv = bias[n];
#pragma unroll
        for (int mi = 0; mi < 4; ++mi) {
            int mbase = m0 + wr * 64 + mi * 16 + lquad * 4;
#pragma unroll
            for (int r = 0; r < 4; ++r)
                out[(size_t)(mbase + r) * O_DIM + n] = acc[mi][ni][r] + bv;
        }
    }
}

// ---------------------------------------------------------------------------
// Kernel 3 (main): 256x256 tile, BK=64, 8 waves, 4-phase/K-tile pipelined
// schedule with counted vmcnt (T3+T4), XOR LDS swizzle via pre-swizzled
// global source (T2, rule #21), setprio around MFMA (T5), XCD swizzle (T1).
//
// LDS layout (byte offsets into smem[131072]):
//   A: buf*32768 + half*16384 + row*128 + pslot*16      (base 0)
//   B: 65536 + buf*32768 + half*16384 + row*128 + pslot*16
// physical pslot = logical_slot ^ (row & 7); global_load_lds writes linearly,
// so the per-lane GLOBAL source address applies the inverse (same) XOR.
//
// Pipeline (steady state), tile t in buf[cur], cur = t&1:
//   ph1: read A0-3,B0-1; stage (t+1).B0 -> buf[!cur]    | MFMA (Mh0,Nh0)
//   ph2: read A4-7;      stage (t+1).B1 -> buf[!cur]    | MFMA (Mh1,Nh0)
//   ph3: read B2-3;      stage (t+2).A0 -> buf[cur]     | MFMA (Mh1,Nh1)
//   ph4:                 stage (t+2).A1 -> buf[cur]     | MFMA (Mh0,Nh1)
//        vmcnt(4)  (leaves only (t+2).A0/A1 in flight)  | barrier
//
// vmcnt ledger: entry of tile t has 4 outstanding ((t+1).A); +4 B, +4 A
// during t; vmcnt(4) drains (t+1).A + (t+1).B.  TAIL FIX (round 1): at
// t == NT_K-2 phases 3/4 stage nothing, so vmcnt(4) would leave the FINAL
// tile's B0/B1 in flight -> stale-B race on the last K-tile (matched the
// observed absmax 33.5). Drain to vmcnt(0) for t >= NT_K-2.
// ---------------------------------------------------------------------------
__global__ __launch_bounds__(512, 2)
void gemm256_kernel(const uint16_t* __restrict__ Ab,
                    const uint16_t* __restrict__ Wb,
                    const float* __restrict__ bias,
                    float* __restrict__ out) {
    __shared__ __align__(16) char smem[131072];
    const int tid = threadIdx.x;
    const int wave = tid >> 6;
    const int lane = tid & 63;

    // T1: XCD-aware bijective swizzle; 1024 wgs % 8 == 0. tn-major chunks so
    // each XCD's 128 blocks share 2 B-panels (4 MiB, fits its private L2).
    int bid = blockIdx.x;
    int swz = (bid & 7) * 128 + (bid >> 3);
    const int tn = swz >> 6;       // 0..15
    const int tm = swz & 63;       // 0..63
    const int m0 = tm * 256;
    const int n0 = tn * 256;

    const int wr = wave >> 2;      // M-half owner (0..1)
    const int wc = wave & 3;       // N-quarter owner (0..3)

    // staging lane constants: lane covers row (+lane>>3), physical slot lane&7,
    // fetching logical slot (lane&7)^(row&7)  [row&7 == lane>>3]
    const int srow = lane >> 3;
    const int sslot = (lane & 7) ^ srow;

    // ds-read lane constants
    const int l15 = lane & 15, q = lane >> 4, l7 = lane & 7;
    const int ps0 = ((q ^ l7) << 4);            // kk=0: logical slot q
    const int ps1 = (((4 | q) ^ l7) << 4);      // kk=1: logical slot 4+q
    const int abase = wr * 16384 + l15 * 128;
    const int bbase = 65536 + (wc >> 1) * 16384 + ((wc & 1) * 64 + l15) * 128;

    f32x4 acc[8][4] = {};
    bf16x8 a[8][2], b[2][2];

#define STAGE_HALF(mat, row0, kt, ldsb)                                       \
    {                                                                         \
        _Pragma("unroll")                                                     \
        for (int j = 0; j < 2; ++j) {                                         \
            const uint16_t* g = (mat) +                                       \
                (size_t)((row0) + j * 64 + wave * 8 + srow) * I_DIM +         \
                (size_t)(kt) * 64 + sslot * 8;                                \
            gll16(g, smem + (ldsb) + (j * 64 + wave * 8) * 128);              \
        }                                                                     \
    }

#define LDA(co, mi) do {                                                      \
        a[mi][0] = *(const bf16x8*)(smem + (co) + abase + (mi) * 2048 + ps0); \
        a[mi][1] = *(const bf16x8*)(smem + (co) + abase + (mi) * 2048 + ps1); \
    } while (0)

#define LDB(co, bi, nn) do {                                                  \
        b[bi][0] = *(const bf16x8*)(smem + (co) + bbase + (nn) * 2048 + ps0); \
        b[bi][1] = *(const bf16x8*)(smem + (co) + bbase + (nn) * 2048 + ps1); \
    } while (0)

#define MFMA_QUAD(MI0, NI0)                                                   \
    _Pragma("unroll")                                                         \
    for (int mi = 0; mi < 4; ++mi)                                            \
        _Pragma("unroll")                                                     \
        for (int ni = 0; ni < 2; ++ni)                                        \
            _Pragma("unroll")                                                 \
            for (int kk = 0; kk < 2; ++kk)                                    \
                acc[(MI0) + mi][(NI0) + ni] =                                 \
                    __builtin_amdgcn_mfma_f32_16x16x32_bf16(                  \
                        a[(MI0) + mi][kk], b[ni][kk],                         \
                        acc[(MI0) + mi][(NI0) + ni], 0, 0, 0);

    // ---- prologue: tile0 fully into buf0, tile1 A-halves into buf1 ----
    STAGE_HALF(Ab, m0,       0, 0);
    STAGE_HALF(Ab, m0 + 128, 0, 16384);
    STAGE_HALF(Wb, n0,       0, 65536);
    STAGE_HALF(Wb, n0 + 128, 0, 65536 + 16384);
    STAGE_HALF(Ab, m0,       1, 32768);
    STAGE_HALF(Ab, m0 + 128, 1, 32768 + 16384);
    asm volatile("s_waitcnt vmcnt(4)" ::: "memory");   // tile0 resident
    __builtin_amdgcn_s_barrier();

#pragma unroll 2
    for (int t = 0; t < NT_K; ++t) {
        const int co = (t & 1) * 32768;   // current buffer
        const int po = co ^ 32768;        // other buffer
        // ---------------- phase 1: (Mh0, Nh0) ----------------
#pragma unroll
        for (int mi = 0; mi < 4; ++mi) LDA(co, mi);
        LDB(co, 0, 0); LDB(co, 1, 1);
        if (t + 1 < NT_K) STAGE_HALF(Wb, n0, t + 1, 65536 + po);
        __builtin_amdgcn_s_barrier();
        __builtin_amdgcn_s_setprio(1);
        MFMA_QUAD(0, 0)
        __builtin_amdgcn_s_setprio(0);
        __builtin_amdgcn_s_barrier();
        // ---------------- phase 2: (Mh1, Nh0) ----------------
#pragma unroll
        for (int mi = 0; mi < 4; ++mi) LDA(co, 4 + mi);
        if (t + 1 < NT_K) STAGE_HALF(Wb, n0 + 128, t + 1, 65536 + po + 16384);
        __builtin_amdgcn_s_barrier();
        __builtin_amdgcn_s_setprio(1);
        MFMA_QUAD(4, 0)
        __builtin_amdgcn_s_setprio(0);
        __builtin_amdgcn_s_barrier();
        // ---------------- phase 3: (Mh1, Nh1) ----------------
        LDB(co, 0, 2); LDB(co, 1, 3);
        if (t + 2 < NT_K) STAGE_HALF(Ab, m0, t + 2, co);
        __builtin_amdgcn_s_barrier();
        __builtin_amdgcn_s_setprio(1);
        MFMA_QUAD(4, 2)
        __builtin_amdgcn_s_setprio(0);
        __builtin_amdgcn_s_barrier();
        // ---------------- phase 4: (Mh0, Nh1) ----------------
        if (t + 2 < NT_K) STAGE_HALF(Ab, m0 + 128, t + 2, co + 16384);
        __builtin_amdgcn_s_barrier();
        __builtin_amdgcn_s_setprio(1);
        MFMA_QUAD(0, 2)
        __builtin_amdgcn_s_setprio(0);
        // TAIL FIX: for t >= NT_K-2 there are no ph3/ph4 stages behind us,
        // so vmcnt(4) would leave the final tile's B in flight. Drain fully.
        if (t < NT_K - 2) {
            asm volatile("s_waitcnt vmcnt(4)" ::: "memory");
        } else {
            asm volatile("s_waitcnt vmcnt(0)" ::: "memory");
        }
        __builtin_amdgcn_s_barrier();
    }

    // ---- epilogue: C/D layout col=lane&15, row=(lane>>4)*4+r ----
    const int lq = lane >> 4;
#pragma unroll
    for (int ni = 0; ni < 4; ++ni) {
        int n = n0 + wc * 64 + ni * 16 + l15;
        float bv = bias[n];
#pragma unroll
        for (int mi = 0; mi < 8; ++mi) {
            int mbase = m0 + wr * 128 + mi * 16 + lq * 4;
#pragma unroll
            for (int r = 0; r < 4; ++r)
                out[(size_t)(mbase + r) * O_DIM + n] = acc[mi][ni][r] + bv;
        }
    }
#undef STAGE_HALF
#undef LDA
#undef LDB
#undef MFMA_QUAD
}

// ---------------------------------------------------------------------------
extern "C" void kernel_launch(void* const* d_in, const int* in_sizes, int n_in,
                              void* d_out, int out_size, void* d_ws,
                              size_t ws_size, hipStream_t stream) {
    const int* qweight = (const int*)d_in[0];
    const float* scales = (const float*)d_in[1];
    const float* lora_up = (const float*)d_in[2];
    const float* lora_down = (const float*)d_in[3];
    const float* bias = (const float*)d_in[4];
    const float* x = (const float*)d_in[5];
    float* out = (float*)d_out;

    uint16_t* w_bf16 = (uint16_t*)d_ws;
    const size_t w_bytes = (size_t)O_DIM * I_DIM * 2;          // 32 MiB
    uint16_t* x_bf16 = (uint16_t*)((char*)d_ws + w_bytes);
    const size_t need_full = w_bytes + (size_t)M_DIM * I_DIM * 2;  // 160 MiB

    build_w_kernel<<<O_DIM * I_DIM / 4 / 256, 256, 0, stream>>>(
        qweight, scales, lora_up, lora_down, w_bf16);

    if (ws_size >= need_full) {
        cvt_x_kernel<<<(size_t)M_DIM * I_DIM / 8 / 256, 256, 0, stream>>>(
            x, x_bf16);
        gemm256_kernel<<<dim3((M_DIM / 256) * (O_DIM / 256)), 512, 0, stream>>>(
            x_bf16, w_bf16, bias, out);
    } else {
        dim3 grid(O_DIM / 128, M_DIM / 128);
        gemm_kernel_f32a<<<grid, 256, 0, stream>>>(x, w_bf16, bias, out);
    }
}